// Round 11
// baseline (197.839 us; speedup 1.0000x reference)
//
#include <hip/hip_runtime.h>
#include <hip/hip_fp16.h>

// reaction_diffusion, 3-kernel pipeline (R22: merged 1024-thr sortgather +
// transpose fused into partition):
//   1. partition (fused transpose prologue): edge loads issued to regs first;
//      each block then transposes 2 x-tiles (64 cols) into xth[N,64] fp16
//      using buf as scratch; then dual-side bucket multisplit (exact R17
//      form: 512->... now with prologue). gcur zeroed by hipMemsetAsync.
//   2. sortgather: ONE 1024-thr block per (side,bucket) [R21 post-mortem:
//      prefetch reorder regressed; only occupancy + work-removal ever won.
//      This merges R17's half-blocks: run staged ONCE (5 int2 regs x 1024 =
//      5120 >= RCAP, was 2x9x512 double-read = 57.6MB), placement 5 rounds
//      all-owned (was 9 half-wasted), LDS 41KB -> 2 blk/CU x 16 waves =
//      32/32 wave slots (same occupancy as R20)]. Gather: exact R20 dual-node
//      pair loop (2x MLP), 16 waves x 8 nodes, oct-split uint4 (1 VMEM per
//      8 payloads), 3-level shfl_xor combine, lanes 0-7 store uint4; lane 0
//      writes colsum.
//   3. final: out[b,v] = tanh(colr*x - msgr + br) + (cold*x - msgd + bd) + x
// side 0 (dest = ei): w_main=wr -> msgr, w_col=wd -> cold
// side 1 (dest = ej): w_main=wd -> msgd, w_col=wr -> colr
// stage-1 payload int2: x=(bkt:9<<23)|(dl:7<<16)|(other:16), y=bf16(wm)<<16|bf16(wc)
// placed payload int: (bf16(wm)<<16)|other:16   -- requires N <= 65536
// NEVER per-edge global atomics (R15: 6.4M atomics = +230us).
// NEVER 64-node partition bins (R18: +13us partition for -2.5us sortgather).
// NEVER unconditional gather over-read/prefetch reorder (R21: +2.5us).
// CAP=80 is a correctness bound: Poisson(32) P(deg>=80) ~ 1e-11.

#define BKT_SHIFT 7
#define BKT_NODES 128
#define RCAP 4608     // per-(side,bucket) run capacity: mean 4096, +8 sigma
#define CAP 80        // per-node fixed slot capacity (deg tail ~1e-11)
#define CH 4096       // partition chunk size (= 8 * 512 threads)
#define NBP 512       // padded per-side bin count (N <= 65536)

__device__ __forceinline__ unsigned bf16_rne(float f) {
    unsigned u = __float_as_uint(f);
    unsigned rb = (u >> 16) & 1u;
    u += 0x7FFFu + rb;
    return u >> 16;
}
__device__ __forceinline__ float bf16_lo(int y) {
    return __uint_as_float(((unsigned)y) << 16);
}
__device__ __forceinline__ float bf16_hi(int y) {
    return __uint_as_float((unsigned)y & 0xFFFF0000u);
}

// kernel 1: dual-side chunked multi-split with fused x-transpose prologue.
// 76KB LDS, 2 blocks/CU. Each block transposes tiles 2*bIdx, 2*bIdx+1.
__global__ void __launch_bounds__(512) partition_kernel(
        const float* __restrict__ x, __half* __restrict__ xth,
        const int* __restrict__ ei, const int* __restrict__ ej,
        const float* __restrict__ wr, const float* __restrict__ wd,
        int* __restrict__ gcur, int2* __restrict__ runs,
        int E, int NB, int N, int ntiles) {
    __shared__ int cnt[2 * NBP];     // 4 KB
    __shared__ int base_a[2 * NBP];  // 4 KB
    __shared__ int gb[2 * NBP];      // 4 KB
    __shared__ int2 buf[2 * CH];     // 64 KB (transpose scratch in prologue)

    int tid = threadIdx.x;
    int e0 = blockIdx.x * CH;
    int ch_len = min(CH, E - e0);

    // issue edge loads first -- they stay in flight under the transpose
    int my_i[8], my_j[8];
    unsigned my_w[8];
    #pragma unroll
    for (int k = 0; k < 8; ++k) {
        int t = tid + k * 512;
        if (t < ch_len) {
            int e = e0 + t;
            my_i[k] = ei[e];
            my_j[k] = ej[e];
            my_w[k] = (bf16_rne(wr[e]) << 16) | bf16_rne(wd[e]);
        } else {
            my_i[k] = -1;
        }
    }

    // fused transpose: 2 tiles per block, buf as float[64][65] scratch
    {
        float (*tile)[65] = (float (*)[65])buf;      // 16.6 KB < 64 KB
        int tx = tid & 63;
        int ty = tid >> 6;                            // 0..7
        for (int tt = blockIdx.x; 2 * tt < ntiles; tt += gridDim.x) {
            #pragma unroll
            for (int hf = 0; hf < 2; ++hf) {
                int ti = 2 * tt + hf;
                if (ti >= ntiles) break;
                int v0 = ti * 64;
                __syncthreads();                      // buf reuse safety
                if (v0 + tx < N) {
                    for (int bb = ty; bb < 64; bb += 8)
                        tile[tx][bb] = x[bb * N + v0 + tx];
                }
                __syncthreads();
                for (int vl = ty; vl < 64; vl += 8) {
                    int v = v0 + vl;
                    if (v < N)
                        xth[(size_t)v * 64 + tx] = __float2half(tile[vl][tx]);
                }
            }
        }
        __syncthreads();
    }
    if (ch_len <= 0) return;

    for (int b = tid; b < 2 * NBP; b += 512) cnt[b] = 0;
    __syncthreads();
    #pragma unroll
    for (int k = 0; k < 8; ++k) {
        if (my_i[k] >= 0) {
            atomicAdd(&cnt[my_i[k] >> BKT_SHIFT], 1);
            atomicAdd(&cnt[NBP + (my_j[k] >> BKT_SHIFT)], 1);
        }
    }
    __syncthreads();
    if (tid < 64) {
        int carry = 0;
        #pragma unroll
        for (int c = 0; c < (2 * NBP) / 64; ++c) {
            int idx = c * 64 + tid;
            int val = cnt[idx];
            int scan = val;
            for (int off = 1; off < 64; off <<= 1) {
                int n = __shfl_up(scan, off, 64);
                if (tid >= off) scan += n;
            }
            int excl = scan - val + carry;
            base_a[idx] = excl;
            cnt[idx] = excl;            // becomes cursor
            carry += __shfl(scan, 63, 64);
        }
    }
    __syncthreads();
    #pragma unroll
    for (int k = 0; k < 8; ++k) {
        if (my_i[k] >= 0) {
            int i = my_i[k], j = my_j[k];
            unsigned wv = my_w[k];
            int b0 = i >> BKT_SHIFT;
            int p0 = atomicAdd(&cnt[b0], 1);
            buf[p0] = make_int2((int)(((unsigned)b0 << 23) | ((unsigned)(i & 127) << 16) | (unsigned)j),
                                (int)wv);
            int b1 = j >> BKT_SHIFT;
            int p1 = atomicAdd(&cnt[NBP + b1], 1);
            buf[p1] = make_int2((int)(((unsigned)b1 << 23) | ((unsigned)(j & 127) << 16) | (unsigned)i),
                                (int)((wv << 16) | (wv >> 16)));
        }
    }
    __syncthreads();
    for (int cb = tid; cb < 2 * NBP; cb += 512) {
        int n = cnt[cb] - base_a[cb];
        if (n > 0) {
            int side = cb >> 9;
            int bkt = cb & (NBP - 1);
            gb[cb] = atomicAdd(&gcur[side * NB + bkt], n);
        }
    }
    __syncthreads();
    int total = 2 * ch_len;
    for (int t = tid; t < total; t += 512) {
        int2 p = buf[t];
        int side = (t >= ch_len) ? 1 : 0;
        int bkt = ((unsigned)p.x >> 23) & 0x1FF;
        int cb = side * NBP + bkt;
        int rank = gb[cb] + (t - base_a[cb]);
        if (rank < RCAP)
            runs[((size_t)(side * NB + bkt)) * RCAP + rank] = p;
    }
}

// accumulate one payload into accumulator set S (weight hi16 of P, uint4 D)
#define ACC8S(S0,S1,S2,S3,S4,S5,S6,S7, P, D)                              \
    {                                                                     \
        float wv_ = bf16_hi(P);                                           \
        float2 f_;                                                        \
        f_ = __half22float2(*(const __half2*)&(D).x);                     \
        S0 = fmaf(wv_, f_.x, S0); S1 = fmaf(wv_, f_.y, S1);               \
        f_ = __half22float2(*(const __half2*)&(D).y);                     \
        S2 = fmaf(wv_, f_.x, S2); S3 = fmaf(wv_, f_.y, S3);               \
        f_ = __half22float2(*(const __half2*)&(D).z);                     \
        S4 = fmaf(wv_, f_.x, S4); S5 = fmaf(wv_, f_.y, S5);               \
        f_ = __half22float2(*(const __half2*)&(D).w);                     \
        S6 = fmaf(wv_, f_.x, S6); S7 = fmaf(wv_, f_.y, S7);               \
    }

#define COMB3(A) { A += __shfl_xor(A, 8); A += __shfl_xor(A, 16); A += __shfl_xor(A, 32); }

// kernel 2: ONE 1024-thr block per (side,bucket). Stage own run once
// (5 int2 nt regs), zero 128-node fixed-cap dst, ONE placement pass (all
// payloads owned), dual-node interleaved oct-split uint4 gather (R20 form).
// 41 KB LDS, 16 waves -> 2 blk/CU = 32/32 wave slots.
__global__ void __launch_bounds__(1024, 8) sortgather_kernel(
        const int* __restrict__ gcur, const int2* __restrict__ runs,
        const __half* __restrict__ xth,
        __half* __restrict__ msg, float* __restrict__ colsum,
        int NB, int N) {
    __shared__ int cur[BKT_NODES];
    __shared__ float csum[BKT_NODES];
    __shared__ int dst[BKT_NODES * CAP];   // 40 KB, node dl owns [dl*CAP, +CAP)

    int sb = blockIdx.x;               // side*NB + b
    int side = (sb >= NB) ? 1 : 0;
    int b = sb - side * NB;
    int v0 = b << BKT_SHIFT;
    int len = min(gcur[sb], RCAP);
    size_t roff = (size_t)sb * RCAP;
    int tid = threadIdx.x;

    // register-stage the whole run: 5 * 1024 = 5120 >= RCAP. Single global
    // read, nontemporal. Valid payloads never have x == -1 (bkt <= 390 < 511).
    int2 my[5];
    #pragma unroll
    for (int k = 0; k < 5; ++k) {
        int t = tid + k * 1024;
        if (t < len) {
            long long raw = __builtin_nontemporal_load((const long long*)(runs + roff + t));
            my[k].x = (int)(unsigned)(raw & 0xFFFFFFFFll);
            my[k].y = (int)(unsigned)((unsigned long long)raw >> 32);
        } else my[k].x = -1;
    }

    // zero cur/csum and the whole dst array (pads/over-reads see w=0, other=0)
    if (tid < BKT_NODES) { cur[tid] = 0; csum[tid] = 0.f; }
    {
        int4* d4 = (int4*)dst;
        for (int idx = tid; idx < (BKT_NODES * CAP) / 4; idx += 1024)
            d4[idx] = make_int4(0, 0, 0, 0);
    }
    __syncthreads();
    // placement: 1 rtn LDS atomic + 1 ds_write + 1 f32 LDS atomic per payload
    #pragma unroll
    for (int k = 0; k < 5; ++k) {
        if (my[k].x != -1) {
            int dl = ((unsigned)my[k].x >> 16) & 0x7F;
            int pos = atomicAdd(&cur[dl], 1);
            if (pos < CAP)
                dst[dl * CAP + pos] =
                    (int)(((unsigned)my[k].y & 0xFFFF0000u) | ((unsigned)my[k].x & 0xFFFFu));
            atomicAdd(&csum[dl], bf16_lo(my[k].y));
        }
    }
    __syncthreads();

    // gather: wave w (0..15) owns nodes dl = w*8..w*8+7, in PAIRS (A,B) for
    // 2x MLP. Oct split: 8 lane-groups of 8; group g processes payload 8*o+g,
    // each lane loads uint4 (16 B = 8 batches). Both nodes run to
    // max(noctA,noctB): dst fully zeroed -> over-read is w=0/row-0 no-op.
    // 3-level shfl_xor combine; lanes 0-7 store dwordx4; lane 0 -> colsum.
    const uint4* __restrict__ xq = (const uint4*)xth;   // [N][8] uint4 rows
    int lane = tid & 63;
    int g  = lane >> 3;                 // payload slot within oct (0..7)
    int bl = lane & 7;                  // 16B chunk: batches 8*bl..8*bl+7
    int wid = tid >> 6;                 // 0..15
    for (int t = 0; t < 8; t += 2) {
        int dllA = wid * 8 + t;
        int dllB = dllA + 1;
        int vA = v0 + dllA;
        int vB = v0 + dllB;
        const int* payA = dst + dllA * CAP + g;
        const int* payB = dst + dllB * CAP + g;
        int noctA = (min(cur[dllA], CAP) + 7) >> 3;
        int noctB = (min(cur[dllB], CAP) + 7) >> 3;
        int noct = max(noctA, noctB);               // <= CAP/8 = 10
        float a0 = 0.f, a1 = 0.f, a2 = 0.f, a3 = 0.f;
        float a4 = 0.f, a5 = 0.f, a6 = 0.f, a7 = 0.f;
        float c0 = 0.f, c1 = 0.f, c2 = 0.f, c3 = 0.f;
        float c4 = 0.f, c5 = 0.f, c6 = 0.f, c7 = 0.f;
        int o = 0;
        for (; o + 2 <= noct; o += 2) {
            int pA0 = payA[8 * o];
            int pA1 = payA[8 * o + 8];
            int pB0 = payB[8 * o];
            int pB1 = payB[8 * o + 8];
            uint4 dA0 = xq[(((size_t)((unsigned)pA0 & 0xFFFFu)) << 3) + bl];
            uint4 dA1 = xq[(((size_t)((unsigned)pA1 & 0xFFFFu)) << 3) + bl];
            uint4 dB0 = xq[(((size_t)((unsigned)pB0 & 0xFFFFu)) << 3) + bl];
            uint4 dB1 = xq[(((size_t)((unsigned)pB1 & 0xFFFFu)) << 3) + bl];
            ACC8S(a0,a1,a2,a3,a4,a5,a6,a7, pA0, dA0)
            ACC8S(a0,a1,a2,a3,a4,a5,a6,a7, pA1, dA1)
            ACC8S(c0,c1,c2,c3,c4,c5,c6,c7, pB0, dB0)
            ACC8S(c0,c1,c2,c3,c4,c5,c6,c7, pB1, dB1)
        }
        if (o < noct) {
            int pA0 = payA[8 * o];
            int pB0 = payB[8 * o];
            uint4 dA0 = xq[(((size_t)((unsigned)pA0 & 0xFFFFu)) << 3) + bl];
            uint4 dB0 = xq[(((size_t)((unsigned)pB0 & 0xFFFFu)) << 3) + bl];
            ACC8S(a0,a1,a2,a3,a4,a5,a6,a7, pA0, dA0)
            ACC8S(c0,c1,c2,c3,c4,c5,c6,c7, pB0, dB0)
        }
        COMB3(a0) COMB3(a1) COMB3(a2) COMB3(a3)
        COMB3(a4) COMB3(a5) COMB3(a6) COMB3(a7)
        COMB3(c0) COMB3(c1) COMB3(c2) COMB3(c3)
        COMB3(c4) COMB3(c5) COMB3(c6) COMB3(c7)
        if (vA < N && lane < 8) {
            __half2 h0 = __floats2half2_rn(a0, a1);
            __half2 h1 = __floats2half2_rn(a2, a3);
            __half2 h2 = __floats2half2_rn(a4, a5);
            __half2 h3 = __floats2half2_rn(a6, a7);
            uint4 st = make_uint4(*(unsigned*)&h0, *(unsigned*)&h1,
                                  *(unsigned*)&h2, *(unsigned*)&h3);
            *(uint4*)(msg + ((size_t)side * N + vA) * 64 + 8 * lane) = st;
        }
        if (vB < N && lane < 8) {
            __half2 h0 = __floats2half2_rn(c0, c1);
            __half2 h1 = __floats2half2_rn(c2, c3);
            __half2 h2 = __floats2half2_rn(c4, c5);
            __half2 h3 = __floats2half2_rn(c6, c7);
            uint4 st = make_uint4(*(unsigned*)&h0, *(unsigned*)&h1,
                                  *(unsigned*)&h2, *(unsigned*)&h3);
            *(uint4*)(msg + ((size_t)side * N + vB) * 64 + 8 * lane) = st;
        }
        if (lane == 0) {
            if (vA < N) colsum[(size_t)side * N + vA] = csum[dllA];
            if (vB < N) colsum[(size_t)side * N + vB] = csum[dllB];
        }
    }
}

// kernel 3: epilogue from original x [64,N]; LDS-transpose fp16 msg tiles.
__global__ void final_kernel(const float* __restrict__ x,
                             const __half* __restrict__ msg,
                             const float* __restrict__ colsum,
                             const float* __restrict__ br, const float* __restrict__ bd,
                             float* __restrict__ out, int N) {
    __shared__ float tr[64][65];
    __shared__ float td[64][65];
    int v0 = blockIdx.x * 64;
    int tx = threadIdx.x;
    int ty = threadIdx.y;
    for (int vl = ty; vl < 64; vl += 16) {
        int v = v0 + vl;
        if (v < N) {
            tr[vl][tx] = __half2float(msg[(size_t)v * 64 + tx]);               // msgr
            td[vl][tx] = __half2float(msg[((size_t)N + v) * 64 + tx]);         // msgd
        }
    }
    __syncthreads();
    int v = v0 + tx;
    if (v < N) {
        float cold = colsum[v];              // side 0: sum wd over e: ei=v
        float colr = colsum[(size_t)N + v];  // side 1: sum wr over e: ej=v
        float brv = br[v], bdv = bd[v];
        for (int b = ty; b < 64; b += 16) {
            float xv = x[b * N + v];
            float r = colr * xv - tr[tx][b] + brv;
            float d = cold * xv - td[tx][b] + bdv;
            out[b * N + v] = tanhf(r) + d + xv;
        }
    }
}

extern "C" void kernel_launch(void* const* d_in, const int* in_sizes, int n_in,
                              void* d_out, int out_size, void* d_ws, size_t ws_size,
                              hipStream_t stream) {
    const float* x  = (const float*)d_in[1];
    const int*   ei = (const int*)d_in[2];
    const int*   ej = (const int*)d_in[3];
    const float* wr = (const float*)d_in[4];
    const float* wd = (const float*)d_in[5];
    const float* br = (const float*)d_in[6];
    const float* bd = (const float*)d_in[7];
    float* out = (float*)d_out;

    int E = in_sizes[2];
    int N = in_sizes[6];
    int NB = (N + BKT_NODES - 1) >> BKT_SHIFT;
    (void)out_size; (void)ws_size; (void)n_in;

    // workspace: xth[N*64 f16] | msg[2*N*64 f16] | colsum[2N f32] | gcur[2NB]
    //          | runs[2*NB*RCAP int2]   (~48 MB)
    char* w = (char*)d_ws;
    __half* xth = (__half*)w;    w += (size_t)N * 64 * 2;
    __half* msg = (__half*)w;    w += (size_t)2 * N * 64 * 2;
    float* colsum = (float*)w;   w += (size_t)2 * N * 4;
    int* gcur   = (int*)w;       w += (size_t)2 * NB * 4;
    w = (char*)(((uintptr_t)w + 15) & ~(uintptr_t)15);
    int2* runs  = (int2*)w;

    int ntiles = (N + 63) / 64;
    int nchunks = (E + CH - 1) / CH;

    hipMemsetAsync(gcur, 0, (size_t)2 * NB * sizeof(int), stream);

    partition_kernel<<<nchunks, 512, 0, stream>>>(x, xth, ei, ej, wr, wd,
                                                  gcur, runs, E, NB, N, ntiles);

    sortgather_kernel<<<2 * NB, 1024, 0, stream>>>(gcur, runs, xth, msg, colsum, NB, N);

    dim3 tb(64, 16);
    final_kernel<<<ntiles, tb, 0, stream>>>(x, msg, colsum, br, bd, out, N);
}

// Round 12
// 193.206 us; speedup vs baseline: 1.0240x; 1.0240x over previous
//
#include <hip/hip_runtime.h>
#include <hip/hip_fp16.h>

// reaction_diffusion, 4-kernel pipeline (R23: R20 + quad-node gather at
// relaxed VGPR bound + vectorized final):
//   1. transpose: x[64,N] -> xth[N,64] fp16 (+ zero gcur)
//   2. partition: dual-side bucket multisplit (512 thr, 76KB LDS, 2 blocks/CU,
//      391 chunks: ONE round)  [exact R17/R20 form]
//   3. sortgather: TWO 512-thr blocks per (side,bucket); block h owns nodes
//      [64h,64h+64). Stage full run (9 int2 nt regs), predicated placement
//      into fixed-cap dst[64*80] (20.5KB LDS). Gather: FOUR nodes interleaved
//      per t-iteration (R22 post-mortem: R20's VGPR=28 under bounds(512,8)
//      shows the compiler serialized the dual-node loads; quad-node + 
//      bounds(512,6) [cap 85 VGPR vs measured 59% ~= 19 waves occupancy]
//      forces 4 loads in flight per o-step at ~unchanged residency).
//      Oct-split uint4 (1 VMEM per 8 payloads), 3-level shfl_xor combine,
//      lanes 0-7 store uint4; lane 0 writes colsum.
//   4. final: out[b,v] = tanh(colr*x - msgr + br) + (cold*x - msgd + bd) + x;
//      msg tiles loaded as __half2 (halved instr count on the 25.6MB stream).
// side 0 (dest = ei): w_main=wr -> msgr, w_col=wd -> cold
// side 1 (dest = ej): w_main=wd -> msgd, w_col=wr -> colr
// stage-1 payload int2: x=(bkt:9<<23)|(dl:7<<16)|(other:16), y=bf16(wm)<<16|bf16(wc)
// placed payload int: (bf16(wm)<<16)|other:16   -- requires N <= 65536
// NEVER per-edge global atomics (R15: 6.4M atomics = +230us).
// NEVER 64-node partition bins (R18: +13us partition for -2.5us sortgather).
// NEVER unconditional prefetch reorder (R21: +2.5us).
// NEVER 1024-thr sortgather blocks (R22: +8us).
// CAP=80 is a correctness bound: Poisson(32) P(deg>=80) ~ 1e-11.

#define BKT_SHIFT 7
#define BKT_NODES 128
#define HALF_NODES 64
#define RCAP 4608     // per-(side,bucket) run capacity: mean 4096, +8 sigma
#define CAP 80        // per-node fixed slot capacity (deg tail ~1e-11)
#define CH 4096       // partition chunk size (= 8 * 512 threads)
#define NBP 512       // padded per-side bin count (N <= 65536)

__device__ __forceinline__ unsigned bf16_rne(float f) {
    unsigned u = __float_as_uint(f);
    unsigned rb = (u >> 16) & 1u;
    u += 0x7FFFu + rb;
    return u >> 16;
}
__device__ __forceinline__ float bf16_lo(int y) {
    return __uint_as_float(((unsigned)y) << 16);
}
__device__ __forceinline__ float bf16_hi(int y) {
    return __uint_as_float((unsigned)y & 0xFFFF0000u);
}

// kernel 1: x [64,N] -> xth [N,64] fp16; also zeroes gcur.
__global__ void transpose_kernel(const float* __restrict__ x, __half* __restrict__ xth,
                                 int* __restrict__ gcur, int ngcur, int N) {
    __shared__ float tile[64][65];
    int v0 = blockIdx.x * 64;
    int tx = threadIdx.x;   // 0..63
    int ty = threadIdx.y;   // 0..15
    int flat = blockIdx.x * 1024 + ty * 64 + tx;
    if (flat < ngcur) gcur[flat] = 0;
    if (v0 + tx < N) {
        for (int b = ty; b < 64; b += 16)
            tile[tx][b] = x[b * N + v0 + tx];
    }
    __syncthreads();
    for (int vl = ty; vl < 64; vl += 16) {
        int v = v0 + vl;
        if (v < N)
            xth[(size_t)v * 64 + tx] = __float2half(tile[vl][tx]);
    }
}

// kernel 2: dual-side chunked multi-split; edges in registers (read once).
// [exact R17 form: 76KB LDS, 2 blocks/CU]
__global__ void __launch_bounds__(512) partition_kernel(
        const int* __restrict__ ei, const int* __restrict__ ej,
        const float* __restrict__ wr, const float* __restrict__ wd,
        int* __restrict__ gcur, int2* __restrict__ runs,
        int E, int NB) {
    __shared__ int cnt[2 * NBP];     // 4 KB
    __shared__ int base_a[2 * NBP];  // 4 KB
    __shared__ int gb[2 * NBP];      // 4 KB
    __shared__ int2 buf[2 * CH];     // 64 KB

    int tid = threadIdx.x;
    int e0 = blockIdx.x * CH;
    int ch_len = min(CH, E - e0);
    if (ch_len <= 0) return;

    int my_i[8], my_j[8];
    unsigned my_w[8];
    #pragma unroll
    for (int k = 0; k < 8; ++k) {
        int t = tid + k * 512;
        if (t < ch_len) {
            int e = e0 + t;
            my_i[k] = ei[e];
            my_j[k] = ej[e];
            my_w[k] = (bf16_rne(wr[e]) << 16) | bf16_rne(wd[e]);
        } else {
            my_i[k] = -1;
        }
    }

    for (int b = tid; b < 2 * NBP; b += 512) cnt[b] = 0;
    __syncthreads();
    #pragma unroll
    for (int k = 0; k < 8; ++k) {
        if (my_i[k] >= 0) {
            atomicAdd(&cnt[my_i[k] >> BKT_SHIFT], 1);
            atomicAdd(&cnt[NBP + (my_j[k] >> BKT_SHIFT)], 1);
        }
    }
    __syncthreads();
    if (tid < 64) {
        int carry = 0;
        #pragma unroll
        for (int c = 0; c < (2 * NBP) / 64; ++c) {
            int idx = c * 64 + tid;
            int val = cnt[idx];
            int scan = val;
            for (int off = 1; off < 64; off <<= 1) {
                int n = __shfl_up(scan, off, 64);
                if (tid >= off) scan += n;
            }
            int excl = scan - val + carry;
            base_a[idx] = excl;
            cnt[idx] = excl;            // becomes cursor
            carry += __shfl(scan, 63, 64);
        }
    }
    __syncthreads();
    #pragma unroll
    for (int k = 0; k < 8; ++k) {
        if (my_i[k] >= 0) {
            int i = my_i[k], j = my_j[k];
            unsigned wv = my_w[k];
            int b0 = i >> BKT_SHIFT;
            int p0 = atomicAdd(&cnt[b0], 1);
            buf[p0] = make_int2((int)(((unsigned)b0 << 23) | ((unsigned)(i & 127) << 16) | (unsigned)j),
                                (int)wv);
            int b1 = j >> BKT_SHIFT;
            int p1 = atomicAdd(&cnt[NBP + b1], 1);
            buf[p1] = make_int2((int)(((unsigned)b1 << 23) | ((unsigned)(j & 127) << 16) | (unsigned)i),
                                (int)((wv << 16) | (wv >> 16)));
        }
    }
    __syncthreads();
    for (int cb = tid; cb < 2 * NBP; cb += 512) {
        int n = cnt[cb] - base_a[cb];
        if (n > 0) {
            int side = cb >> 9;
            int bkt = cb & (NBP - 1);
            gb[cb] = atomicAdd(&gcur[side * NB + bkt], n);
        }
    }
    __syncthreads();
    int total = 2 * ch_len;
    for (int t = tid; t < total; t += 512) {
        int2 p = buf[t];
        int side = (t >= ch_len) ? 1 : 0;
        int bkt = ((unsigned)p.x >> 23) & 0x1FF;
        int cb = side * NBP + bkt;
        int rank = gb[cb] + (t - base_a[cb]);
        if (rank < RCAP)
            runs[((size_t)(side * NB + bkt)) * RCAP + rank] = p;
    }
}

// accumulate one payload into accumulator set S (weight hi16 of P, uint4 D)
#define ACC8S(S0,S1,S2,S3,S4,S5,S6,S7, P, D)                              \
    {                                                                     \
        float wv_ = bf16_hi(P);                                           \
        float2 f_;                                                        \
        f_ = __half22float2(*(const __half2*)&(D).x);                     \
        S0 = fmaf(wv_, f_.x, S0); S1 = fmaf(wv_, f_.y, S1);               \
        f_ = __half22float2(*(const __half2*)&(D).y);                     \
        S2 = fmaf(wv_, f_.x, S2); S3 = fmaf(wv_, f_.y, S3);               \
        f_ = __half22float2(*(const __half2*)&(D).z);                     \
        S4 = fmaf(wv_, f_.x, S4); S5 = fmaf(wv_, f_.y, S5);               \
        f_ = __half22float2(*(const __half2*)&(D).w);                     \
        S6 = fmaf(wv_, f_.x, S6); S7 = fmaf(wv_, f_.y, S7);               \
    }

#define COMB3(A) { A += __shfl_xor(A, 8); A += __shfl_xor(A, 16); A += __shfl_xor(A, 32); }

#define STORE8(S0,S1,S2,S3,S4,S5,S6,S7, V)                                \
    if ((V) < N && lane < 8) {                                            \
        __half2 h0 = __floats2half2_rn(S0, S1);                           \
        __half2 h1 = __floats2half2_rn(S2, S3);                           \
        __half2 h2 = __floats2half2_rn(S4, S5);                           \
        __half2 h3 = __floats2half2_rn(S6, S7);                           \
        uint4 st = make_uint4(*(unsigned*)&h0, *(unsigned*)&h1,           \
                              *(unsigned*)&h2, *(unsigned*)&h3);          \
        *(uint4*)(msg + ((size_t)side * N + (V)) * 64 + 8 * lane) = st;   \
    }

// kernel 3: 2 blocks per (side,bucket); block h owns nodes [64h, 64h+64).
// Stage full run into 9 int2 regs (nt), zero 64-node fixed-cap dst, ONE
// predicated placement pass, QUAD-node interleaved oct-split uint4 gather.
// ~21 KB LDS, 512 thr, launch_bounds(512,6): VGPR cap 85 (occupancy measured
// ~19 waves < 24-wave cap, so residency ~unchanged; MLP per wave up).
__global__ void __launch_bounds__(512, 6) sortgather_kernel(
        const int* __restrict__ gcur, const int2* __restrict__ runs,
        const __half* __restrict__ xth,
        __half* __restrict__ msg, float* __restrict__ colsum,
        int NB, int N) {
    __shared__ int cur[HALF_NODES];
    __shared__ float csum[HALF_NODES];
    __shared__ int dst[HALF_NODES * CAP];   // 20 KB, node dll owns [dll*CAP, +CAP)

    int blk = blockIdx.x;
    int sb = blk >> 1;                 // side*NB + b
    int h  = blk & 1;                  // bucket half
    int side = (sb >= NB) ? 1 : 0;
    int b = sb - side * NB;
    int v0 = (b << BKT_SHIFT) + h * HALF_NODES;
    int len = min(gcur[sb], RCAP);
    size_t roff = (size_t)sb * RCAP;
    int tid = threadIdx.x;

    // register-stage the whole run: 9 * 512 = 4608 = RCAP. Single global read,
    // nontemporal. Valid payloads never have x == -1 (bkt field <= 390 < 511).
    int2 my[9];
    #pragma unroll
    for (int k = 0; k < 9; ++k) {
        int t = tid + k * 512;
        if (t < len) {
            long long raw = __builtin_nontemporal_load((const long long*)(runs + roff + t));
            my[k].x = (int)(unsigned)(raw & 0xFFFFFFFFll);
            my[k].y = (int)(unsigned)((unsigned long long)raw >> 32);
        } else my[k].x = -1;
    }

    // zero cur/csum and the whole dst array (pads/over-reads see w=0, other=0)
    if (tid < HALF_NODES) { cur[tid] = 0; csum[tid] = 0.f; }
    {
        int4* d4 = (int4*)dst;
        for (int idx = tid; idx < (HALF_NODES * CAP) / 4; idx += 512)
            d4[idx] = make_int4(0, 0, 0, 0);
    }
    __syncthreads();
    // placement: predicated on ownership (dl's half == h).
    #pragma unroll
    for (int k = 0; k < 9; ++k) {
        if (my[k].x != -1) {
            int dl = ((unsigned)my[k].x >> 16) & 0x7F;
            if ((dl >> 6) == h) {
                int dll = dl & (HALF_NODES - 1);
                int pos = atomicAdd(&cur[dll], 1);
                if (pos < CAP)
                    dst[dll * CAP + pos] =
                        (int)(((unsigned)my[k].y & 0xFFFF0000u) | ((unsigned)my[k].x & 0xFFFFu));
                atomicAdd(&csum[dll], bf16_lo(my[k].y));
            }
        }
    }
    __syncthreads();

    // gather: wave w owns nodes dll = w*8..w*8+7, processed FOUR at a time
    // (A,B,C,D) for 4x MLP. Oct split: 8 lane-groups of 8; group g processes
    // payload 8*o+g, each lane loads uint4 (16 B = 8 batches). All nodes run
    // to max noct: dst fully zeroed -> over-read is w=0/row-0 no-op.
    // 3-level shfl_xor combine; lanes 0-7 store dwordx4; lane 0 -> colsum.
    const uint4* __restrict__ xq = (const uint4*)xth;   // [N][8] uint4 rows
    int lane = tid & 63;
    int g  = lane >> 3;                 // payload slot within oct (0..7)
    int bl = lane & 7;                  // 16B chunk: batches 8*bl..8*bl+7
    int wid = tid >> 6;
    for (int t = 0; t < HALF_NODES / 8; t += 4) {
        int dllA = wid * (HALF_NODES / 8) + t;
        int dllB = dllA + 1;
        int dllC = dllA + 2;
        int dllD = dllA + 3;
        const int* payA = dst + dllA * CAP + g;
        const int* payB = dst + dllB * CAP + g;
        const int* payC = dst + dllC * CAP + g;
        const int* payD = dst + dllD * CAP + g;
        int no = max(max(min(cur[dllA], CAP), min(cur[dllB], CAP)),
                     max(min(cur[dllC], CAP), min(cur[dllD], CAP)));
        int noct = (no + 7) >> 3;                   // <= CAP/8 = 10
        float a0 = 0.f, a1 = 0.f, a2 = 0.f, a3 = 0.f;
        float a4 = 0.f, a5 = 0.f, a6 = 0.f, a7 = 0.f;
        float c0 = 0.f, c1 = 0.f, c2 = 0.f, c3 = 0.f;
        float c4 = 0.f, c5 = 0.f, c6 = 0.f, c7 = 0.f;
        float e0 = 0.f, e1 = 0.f, e2 = 0.f, e3 = 0.f;
        float e4 = 0.f, e5 = 0.f, e6 = 0.f, e7 = 0.f;
        float f0 = 0.f, f1 = 0.f, f2 = 0.f, f3 = 0.f;
        float f4 = 0.f, f5 = 0.f, f6 = 0.f, f7 = 0.f;
        for (int o = 0; o < noct; ++o) {
            int pA = payA[8 * o];
            int pB = payB[8 * o];
            int pC = payC[8 * o];
            int pD = payD[8 * o];
            uint4 dA = xq[(((size_t)((unsigned)pA & 0xFFFFu)) << 3) + bl];
            uint4 dB = xq[(((size_t)((unsigned)pB & 0xFFFFu)) << 3) + bl];
            uint4 dC = xq[(((size_t)((unsigned)pC & 0xFFFFu)) << 3) + bl];
            uint4 dD = xq[(((size_t)((unsigned)pD & 0xFFFFu)) << 3) + bl];
            ACC8S(a0,a1,a2,a3,a4,a5,a6,a7, pA, dA)
            ACC8S(c0,c1,c2,c3,c4,c5,c6,c7, pB, dB)
            ACC8S(e0,e1,e2,e3,e4,e5,e6,e7, pC, dC)
            ACC8S(f0,f1,f2,f3,f4,f5,f6,f7, pD, dD)
        }
        COMB3(a0) COMB3(a1) COMB3(a2) COMB3(a3)
        COMB3(a4) COMB3(a5) COMB3(a6) COMB3(a7)
        COMB3(c0) COMB3(c1) COMB3(c2) COMB3(c3)
        COMB3(c4) COMB3(c5) COMB3(c6) COMB3(c7)
        COMB3(e0) COMB3(e1) COMB3(e2) COMB3(e3)
        COMB3(e4) COMB3(e5) COMB3(e6) COMB3(e7)
        COMB3(f0) COMB3(f1) COMB3(f2) COMB3(f3)
        COMB3(f4) COMB3(f5) COMB3(f6) COMB3(f7)
        int vA = v0 + dllA, vB = v0 + dllB, vC = v0 + dllC, vD = v0 + dllD;
        STORE8(a0,a1,a2,a3,a4,a5,a6,a7, vA)
        STORE8(c0,c1,c2,c3,c4,c5,c6,c7, vB)
        STORE8(e0,e1,e2,e3,e4,e5,e6,e7, vC)
        STORE8(f0,f1,f2,f3,f4,f5,f6,f7, vD)
        if (lane == 0) {
            if (vA < N) colsum[(size_t)side * N + vA] = csum[dllA];
            if (vB < N) colsum[(size_t)side * N + vB] = csum[dllB];
            if (vC < N) colsum[(size_t)side * N + vC] = csum[dllC];
            if (vD < N) colsum[(size_t)side * N + vD] = csum[dllD];
        }
    }
}

// kernel 4: epilogue from original x [64,N]; LDS-transpose fp16 msg tiles.
// msg loaded as __half2 (halved load-instr count on the 25.6MB stream).
__global__ void final_kernel(const float* __restrict__ x,
                             const __half* __restrict__ msg,
                             const float* __restrict__ colsum,
                             const float* __restrict__ br, const float* __restrict__ bd,
                             float* __restrict__ out, int N) {
    __shared__ float tr[64][65];
    __shared__ float td[64][65];
    int v0 = blockIdx.x * 64;
    int tx = threadIdx.x;
    int ty = threadIdx.y;
    // vectorized tile fill: 1024 threads, each loads one __half2 (2 batches)
    // per array per pass; 2 passes cover 64 rows x 32 pairs.
    int flat = ty * 64 + tx;            // 0..1023
    int r = flat >> 5;                  // row within pass (0..31)
    int p = flat & 31;                  // batch pair (0..31)
    #pragma unroll
    for (int pass = 0; pass < 2; ++pass) {
        int vl = pass * 32 + r;
        int v = v0 + vl;
        if (v < N) {
            float2 mr = __half22float2(*(const __half2*)(msg + (size_t)v * 64 + 2 * p));
            float2 md = __half22float2(*(const __half2*)(msg + ((size_t)N + v) * 64 + 2 * p));
            tr[vl][2 * p] = mr.x; tr[vl][2 * p + 1] = mr.y;
            td[vl][2 * p] = md.x; td[vl][2 * p + 1] = md.y;
        }
    }
    __syncthreads();
    int v = v0 + tx;
    if (v < N) {
        float cold = colsum[v];              // side 0: sum wd over e: ei=v
        float colr = colsum[(size_t)N + v];  // side 1: sum wr over e: ej=v
        float brv = br[v], bdv = bd[v];
        for (int b = ty; b < 64; b += 16) {
            float xv = x[b * N + v];
            float r2 = colr * xv - tr[tx][b] + brv;
            float d2 = cold * xv - td[tx][b] + bdv;
            out[b * N + v] = tanhf(r2) + d2 + xv;
        }
    }
}

extern "C" void kernel_launch(void* const* d_in, const int* in_sizes, int n_in,
                              void* d_out, int out_size, void* d_ws, size_t ws_size,
                              hipStream_t stream) {
    const float* x  = (const float*)d_in[1];
    const int*   ei = (const int*)d_in[2];
    const int*   ej = (const int*)d_in[3];
    const float* wr = (const float*)d_in[4];
    const float* wd = (const float*)d_in[5];
    const float* br = (const float*)d_in[6];
    const float* bd = (const float*)d_in[7];
    float* out = (float*)d_out;

    int E = in_sizes[2];
    int N = in_sizes[6];
    int NB = (N + BKT_NODES - 1) >> BKT_SHIFT;
    (void)out_size; (void)ws_size; (void)n_in;

    // workspace: xth[N*64 f16] | msg[2*N*64 f16] | colsum[2N f32] | gcur[2NB]
    //          | runs[2*NB*RCAP int2]   (~48 MB)
    char* w = (char*)d_ws;
    __half* xth = (__half*)w;    w += (size_t)N * 64 * 2;
    __half* msg = (__half*)w;    w += (size_t)2 * N * 64 * 2;
    float* colsum = (float*)w;   w += (size_t)2 * N * 4;
    int* gcur   = (int*)w;       w += (size_t)2 * NB * 4;
    w = (char*)(((uintptr_t)w + 15) & ~(uintptr_t)15);
    int2* runs  = (int2*)w;

    dim3 tb(64, 16);
    int ntiles = (N + 63) / 64;
    transpose_kernel<<<ntiles, tb, 0, stream>>>(x, xth, gcur, 2 * NB, N);

    int nchunks = (E + CH - 1) / CH;
    partition_kernel<<<nchunks, 512, 0, stream>>>(ei, ej, wr, wd, gcur, runs, E, NB);

    sortgather_kernel<<<4 * NB, 512, 0, stream>>>(gcur, runs, xth, msg, colsum, NB, N);

    final_kernel<<<ntiles, tb, 0, stream>>>(x, msg, colsum, br, bd, out, N);
}

// Round 13
// 187.852 us; speedup vs baseline: 1.0532x; 1.0285x over previous
//
#include <hip/hip_runtime.h>
#include <hip/hip_fp16.h>

// reaction_diffusion, 4-kernel pipeline (R24: composition of proven optima —
// exact R20 sortgather + R23 vectorized final):
//   1. transpose: x[64,N] -> xth[N,64] fp16 (+ zero gcur)
//   2. partition: dual-side bucket multisplit (512 thr, 76KB LDS, 2 blocks/CU,
//      391 chunks: ONE round)  [exact R17/R20 form]
//   3. sortgather: TWO 512-thr blocks per (side,bucket); block h owns nodes
//      [64h,64h+64). Stage full run (9 int2 nt regs), predicated placement
//      into fixed-cap dst[64*80] (20.5KB LDS -> 4 blk/CU). Gather: DUAL-node
//      interleave — the measured MLP optimum (R20/R23 ladder: 1-node=69.5,
//      2-node=65.3, 4-node=69.7us; 4-way max-noct waste + occupancy drop beat
//      the extra MLP). bounds(512,8), VGPR 28, occ 59%. Oct-split uint4
//      (1 VMEM per 8 payloads), 3-level shfl_xor combine, lanes 0-7 store
//      uint4; lane 0 writes colsum.
//   4. final: out[b,v] = tanh(colr*x - msgr + br) + (cold*x - msgd + bd) + x;
//      msg tiles loaded as __half2 (R23: -1.5us measured).
// side 0 (dest = ei): w_main=wr -> msgr, w_col=wd -> cold
// side 1 (dest = ej): w_main=wd -> msgd, w_col=wr -> colr
// stage-1 payload int2: x=(bkt:9<<23)|(dl:7<<16)|(other:16), y=bf16(wm)<<16|bf16(wc)
// placed payload int: (bf16(wm)<<16)|other:16   -- requires N <= 65536
// NEVER per-edge global atomics (R15: 6.4M atomics = +230us).
// NEVER 64-node partition bins (R18: +13us partition for -2.5us sortgather).
// NEVER unconditional prefetch reorder (R21: +2.5us).
// NEVER 1024-thr sortgather blocks (R22: +8us).
// NEVER quad-node gather (R23: +4.4us — max-noct waste + occupancy drop).
// CAP=80 is a correctness bound: Poisson(32) P(deg>=80) ~ 1e-11.

#define BKT_SHIFT 7
#define BKT_NODES 128
#define HALF_NODES 64
#define RCAP 4608     // per-(side,bucket) run capacity: mean 4096, +8 sigma
#define CAP 80        // per-node fixed slot capacity (deg tail ~1e-11)
#define CH 4096       // partition chunk size (= 8 * 512 threads)
#define NBP 512       // padded per-side bin count (N <= 65536)

__device__ __forceinline__ unsigned bf16_rne(float f) {
    unsigned u = __float_as_uint(f);
    unsigned rb = (u >> 16) & 1u;
    u += 0x7FFFu + rb;
    return u >> 16;
}
__device__ __forceinline__ float bf16_lo(int y) {
    return __uint_as_float(((unsigned)y) << 16);
}
__device__ __forceinline__ float bf16_hi(int y) {
    return __uint_as_float((unsigned)y & 0xFFFF0000u);
}

// kernel 1: x [64,N] -> xth [N,64] fp16; also zeroes gcur.
__global__ void transpose_kernel(const float* __restrict__ x, __half* __restrict__ xth,
                                 int* __restrict__ gcur, int ngcur, int N) {
    __shared__ float tile[64][65];
    int v0 = blockIdx.x * 64;
    int tx = threadIdx.x;   // 0..63
    int ty = threadIdx.y;   // 0..15
    int flat = blockIdx.x * 1024 + ty * 64 + tx;
    if (flat < ngcur) gcur[flat] = 0;
    if (v0 + tx < N) {
        for (int b = ty; b < 64; b += 16)
            tile[tx][b] = x[b * N + v0 + tx];
    }
    __syncthreads();
    for (int vl = ty; vl < 64; vl += 16) {
        int v = v0 + vl;
        if (v < N)
            xth[(size_t)v * 64 + tx] = __float2half(tile[vl][tx]);
    }
}

// kernel 2: dual-side chunked multi-split; edges in registers (read once).
// [exact R17 form: 76KB LDS, 2 blocks/CU]
__global__ void __launch_bounds__(512) partition_kernel(
        const int* __restrict__ ei, const int* __restrict__ ej,
        const float* __restrict__ wr, const float* __restrict__ wd,
        int* __restrict__ gcur, int2* __restrict__ runs,
        int E, int NB) {
    __shared__ int cnt[2 * NBP];     // 4 KB
    __shared__ int base_a[2 * NBP];  // 4 KB
    __shared__ int gb[2 * NBP];      // 4 KB
    __shared__ int2 buf[2 * CH];     // 64 KB

    int tid = threadIdx.x;
    int e0 = blockIdx.x * CH;
    int ch_len = min(CH, E - e0);
    if (ch_len <= 0) return;

    int my_i[8], my_j[8];
    unsigned my_w[8];
    #pragma unroll
    for (int k = 0; k < 8; ++k) {
        int t = tid + k * 512;
        if (t < ch_len) {
            int e = e0 + t;
            my_i[k] = ei[e];
            my_j[k] = ej[e];
            my_w[k] = (bf16_rne(wr[e]) << 16) | bf16_rne(wd[e]);
        } else {
            my_i[k] = -1;
        }
    }

    for (int b = tid; b < 2 * NBP; b += 512) cnt[b] = 0;
    __syncthreads();
    #pragma unroll
    for (int k = 0; k < 8; ++k) {
        if (my_i[k] >= 0) {
            atomicAdd(&cnt[my_i[k] >> BKT_SHIFT], 1);
            atomicAdd(&cnt[NBP + (my_j[k] >> BKT_SHIFT)], 1);
        }
    }
    __syncthreads();
    if (tid < 64) {
        int carry = 0;
        #pragma unroll
        for (int c = 0; c < (2 * NBP) / 64; ++c) {
            int idx = c * 64 + tid;
            int val = cnt[idx];
            int scan = val;
            for (int off = 1; off < 64; off <<= 1) {
                int n = __shfl_up(scan, off, 64);
                if (tid >= off) scan += n;
            }
            int excl = scan - val + carry;
            base_a[idx] = excl;
            cnt[idx] = excl;            // becomes cursor
            carry += __shfl(scan, 63, 64);
        }
    }
    __syncthreads();
    #pragma unroll
    for (int k = 0; k < 8; ++k) {
        if (my_i[k] >= 0) {
            int i = my_i[k], j = my_j[k];
            unsigned wv = my_w[k];
            int b0 = i >> BKT_SHIFT;
            int p0 = atomicAdd(&cnt[b0], 1);
            buf[p0] = make_int2((int)(((unsigned)b0 << 23) | ((unsigned)(i & 127) << 16) | (unsigned)j),
                                (int)wv);
            int b1 = j >> BKT_SHIFT;
            int p1 = atomicAdd(&cnt[NBP + b1], 1);
            buf[p1] = make_int2((int)(((unsigned)b1 << 23) | ((unsigned)(j & 127) << 16) | (unsigned)i),
                                (int)((wv << 16) | (wv >> 16)));
        }
    }
    __syncthreads();
    for (int cb = tid; cb < 2 * NBP; cb += 512) {
        int n = cnt[cb] - base_a[cb];
        if (n > 0) {
            int side = cb >> 9;
            int bkt = cb & (NBP - 1);
            gb[cb] = atomicAdd(&gcur[side * NB + bkt], n);
        }
    }
    __syncthreads();
    int total = 2 * ch_len;
    for (int t = tid; t < total; t += 512) {
        int2 p = buf[t];
        int side = (t >= ch_len) ? 1 : 0;
        int bkt = ((unsigned)p.x >> 23) & 0x1FF;
        int cb = side * NBP + bkt;
        int rank = gb[cb] + (t - base_a[cb]);
        if (rank < RCAP)
            runs[((size_t)(side * NB + bkt)) * RCAP + rank] = p;
    }
}

// accumulate one payload into accumulator set S (weight hi16 of P, uint4 D)
#define ACC8S(S0,S1,S2,S3,S4,S5,S6,S7, P, D)                              \
    {                                                                     \
        float wv_ = bf16_hi(P);                                           \
        float2 f_;                                                        \
        f_ = __half22float2(*(const __half2*)&(D).x);                     \
        S0 = fmaf(wv_, f_.x, S0); S1 = fmaf(wv_, f_.y, S1);               \
        f_ = __half22float2(*(const __half2*)&(D).y);                     \
        S2 = fmaf(wv_, f_.x, S2); S3 = fmaf(wv_, f_.y, S3);               \
        f_ = __half22float2(*(const __half2*)&(D).z);                     \
        S4 = fmaf(wv_, f_.x, S4); S5 = fmaf(wv_, f_.y, S5);               \
        f_ = __half22float2(*(const __half2*)&(D).w);                     \
        S6 = fmaf(wv_, f_.x, S6); S7 = fmaf(wv_, f_.y, S7);               \
    }

#define COMB3(A) { A += __shfl_xor(A, 8); A += __shfl_xor(A, 16); A += __shfl_xor(A, 32); }

// kernel 3: 2 blocks per (side,bucket); block h owns nodes [64h, 64h+64).
// Stage full run into 9 int2 regs (nt), zero 64-node fixed-cap dst, ONE
// predicated placement pass, dual-node interleaved oct-split uint4 gather.
// ~21 KB LDS, 512 thr, 4 blk/CU (wave-slot cap).  [exact R20 form]
__global__ void __launch_bounds__(512, 8) sortgather_kernel(
        const int* __restrict__ gcur, const int2* __restrict__ runs,
        const __half* __restrict__ xth,
        __half* __restrict__ msg, float* __restrict__ colsum,
        int NB, int N) {
    __shared__ int cur[HALF_NODES];
    __shared__ float csum[HALF_NODES];
    __shared__ int dst[HALF_NODES * CAP];   // 20 KB, node dll owns [dll*CAP, +CAP)

    int blk = blockIdx.x;
    int sb = blk >> 1;                 // side*NB + b
    int h  = blk & 1;                  // bucket half
    int side = (sb >= NB) ? 1 : 0;
    int b = sb - side * NB;
    int v0 = (b << BKT_SHIFT) + h * HALF_NODES;
    int len = min(gcur[sb], RCAP);
    size_t roff = (size_t)sb * RCAP;
    int tid = threadIdx.x;

    // register-stage the whole run: 9 * 512 = 4608 = RCAP. Single global read,
    // nontemporal. Valid payloads never have x == -1 (bkt field <= 390 < 511).
    int2 my[9];
    #pragma unroll
    for (int k = 0; k < 9; ++k) {
        int t = tid + k * 512;
        if (t < len) {
            long long raw = __builtin_nontemporal_load((const long long*)(runs + roff + t));
            my[k].x = (int)(unsigned)(raw & 0xFFFFFFFFll);
            my[k].y = (int)(unsigned)((unsigned long long)raw >> 32);
        } else my[k].x = -1;
    }

    // zero cur/csum and the whole dst array (pads/over-reads see w=0, other=0)
    if (tid < HALF_NODES) { cur[tid] = 0; csum[tid] = 0.f; }
    {
        int4* d4 = (int4*)dst;
        for (int idx = tid; idx < (HALF_NODES * CAP) / 4; idx += 512)
            d4[idx] = make_int4(0, 0, 0, 0);
    }
    __syncthreads();
    // placement: predicated on ownership (dl's half == h).
    #pragma unroll
    for (int k = 0; k < 9; ++k) {
        if (my[k].x != -1) {
            int dl = ((unsigned)my[k].x >> 16) & 0x7F;
            if ((dl >> 6) == h) {
                int dll = dl & (HALF_NODES - 1);
                int pos = atomicAdd(&cur[dll], 1);
                if (pos < CAP)
                    dst[dll * CAP + pos] =
                        (int)(((unsigned)my[k].y & 0xFFFF0000u) | ((unsigned)my[k].x & 0xFFFFu));
                atomicAdd(&csum[dll], bf16_lo(my[k].y));
            }
        }
    }
    __syncthreads();

    // gather: wave w owns nodes dll = w*8..w*8+7, processed in PAIRS (A,B)
    // to double outstanding VMEM per wave. Oct split: 8 lane-groups of 8;
    // group g processes payload 8*o+g, each lane loads uint4 (16 B = 8
    // batches). Both nodes run to max(noctA,noctB): dst fully zeroed ->
    // over-read is w=0/row-0 no-op. 3-level shfl_xor combine; lanes 0-7
    // store dwordx4; lane 0 writes colsum.
    const uint4* __restrict__ xq = (const uint4*)xth;   // [N][8] uint4 rows
    int lane = tid & 63;
    int g  = lane >> 3;                 // payload slot within oct (0..7)
    int bl = lane & 7;                  // 16B chunk: batches 8*bl..8*bl+7
    int wid = tid >> 6;
    for (int t = 0; t < HALF_NODES / 8; t += 2) {
        int dllA = wid * (HALF_NODES / 8) + t;
        int dllB = dllA + 1;
        int vA = v0 + dllA;
        int vB = v0 + dllB;
        const int* payA = dst + dllA * CAP + g;
        const int* payB = dst + dllB * CAP + g;
        int noctA = (min(cur[dllA], CAP) + 7) >> 3;
        int noctB = (min(cur[dllB], CAP) + 7) >> 3;
        int noct = max(noctA, noctB);               // <= CAP/8 = 10
        float a0 = 0.f, a1 = 0.f, a2 = 0.f, a3 = 0.f;
        float a4 = 0.f, a5 = 0.f, a6 = 0.f, a7 = 0.f;
        float c0 = 0.f, c1 = 0.f, c2 = 0.f, c3 = 0.f;
        float c4 = 0.f, c5 = 0.f, c6 = 0.f, c7 = 0.f;
        int o = 0;
        for (; o + 2 <= noct; o += 2) {
            int pA0 = payA[8 * o];
            int pA1 = payA[8 * o + 8];
            int pB0 = payB[8 * o];
            int pB1 = payB[8 * o + 8];
            uint4 dA0 = xq[(((size_t)((unsigned)pA0 & 0xFFFFu)) << 3) + bl];
            uint4 dA1 = xq[(((size_t)((unsigned)pA1 & 0xFFFFu)) << 3) + bl];
            uint4 dB0 = xq[(((size_t)((unsigned)pB0 & 0xFFFFu)) << 3) + bl];
            uint4 dB1 = xq[(((size_t)((unsigned)pB1 & 0xFFFFu)) << 3) + bl];
            ACC8S(a0,a1,a2,a3,a4,a5,a6,a7, pA0, dA0)
            ACC8S(a0,a1,a2,a3,a4,a5,a6,a7, pA1, dA1)
            ACC8S(c0,c1,c2,c3,c4,c5,c6,c7, pB0, dB0)
            ACC8S(c0,c1,c2,c3,c4,c5,c6,c7, pB1, dB1)
        }
        if (o < noct) {
            int pA0 = payA[8 * o];
            int pB0 = payB[8 * o];
            uint4 dA0 = xq[(((size_t)((unsigned)pA0 & 0xFFFFu)) << 3) + bl];
            uint4 dB0 = xq[(((size_t)((unsigned)pB0 & 0xFFFFu)) << 3) + bl];
            ACC8S(a0,a1,a2,a3,a4,a5,a6,a7, pA0, dA0)
            ACC8S(c0,c1,c2,c3,c4,c5,c6,c7, pB0, dB0)
        }
        COMB3(a0) COMB3(a1) COMB3(a2) COMB3(a3)
        COMB3(a4) COMB3(a5) COMB3(a6) COMB3(a7)
        COMB3(c0) COMB3(c1) COMB3(c2) COMB3(c3)
        COMB3(c4) COMB3(c5) COMB3(c6) COMB3(c7)
        if (vA < N && lane < 8) {
            __half2 h0 = __floats2half2_rn(a0, a1);
            __half2 h1 = __floats2half2_rn(a2, a3);
            __half2 h2 = __floats2half2_rn(a4, a5);
            __half2 h3 = __floats2half2_rn(a6, a7);
            uint4 st = make_uint4(*(unsigned*)&h0, *(unsigned*)&h1,
                                  *(unsigned*)&h2, *(unsigned*)&h3);
            *(uint4*)(msg + ((size_t)side * N + vA) * 64 + 8 * lane) = st;
        }
        if (vB < N && lane < 8) {
            __half2 h0 = __floats2half2_rn(c0, c1);
            __half2 h1 = __floats2half2_rn(c2, c3);
            __half2 h2 = __floats2half2_rn(c4, c5);
            __half2 h3 = __floats2half2_rn(c6, c7);
            uint4 st = make_uint4(*(unsigned*)&h0, *(unsigned*)&h1,
                                  *(unsigned*)&h2, *(unsigned*)&h3);
            *(uint4*)(msg + ((size_t)side * N + vB) * 64 + 8 * lane) = st;
        }
        if (lane == 0) {
            if (vA < N) colsum[(size_t)side * N + vA] = csum[dllA];
            if (vB < N) colsum[(size_t)side * N + vB] = csum[dllB];
        }
    }
}

// kernel 4: epilogue from original x [64,N]; LDS-transpose fp16 msg tiles.
// msg loaded as __half2 (R23: halved load-instr count, -1.5us measured).
__global__ void final_kernel(const float* __restrict__ x,
                             const __half* __restrict__ msg,
                             const float* __restrict__ colsum,
                             const float* __restrict__ br, const float* __restrict__ bd,
                             float* __restrict__ out, int N) {
    __shared__ float tr[64][65];
    __shared__ float td[64][65];
    int v0 = blockIdx.x * 64;
    int tx = threadIdx.x;
    int ty = threadIdx.y;
    // vectorized tile fill: 1024 threads, each loads one __half2 (2 batches)
    // per array per pass; 2 passes cover 64 rows x 32 pairs.
    int flat = ty * 64 + tx;            // 0..1023
    int r = flat >> 5;                  // row within pass (0..31)
    int p = flat & 31;                  // batch pair (0..31)
    #pragma unroll
    for (int pass = 0; pass < 2; ++pass) {
        int vl = pass * 32 + r;
        int v = v0 + vl;
        if (v < N) {
            float2 mr = __half22float2(*(const __half2*)(msg + (size_t)v * 64 + 2 * p));
            float2 md = __half22float2(*(const __half2*)(msg + ((size_t)N + v) * 64 + 2 * p));
            tr[vl][2 * p] = mr.x; tr[vl][2 * p + 1] = mr.y;
            td[vl][2 * p] = md.x; td[vl][2 * p + 1] = md.y;
        }
    }
    __syncthreads();
    int v = v0 + tx;
    if (v < N) {
        float cold = colsum[v];              // side 0: sum wd over e: ei=v
        float colr = colsum[(size_t)N + v];  // side 1: sum wr over e: ej=v
        float brv = br[v], bdv = bd[v];
        for (int b = ty; b < 64; b += 16) {
            float xv = x[b * N + v];
            float r2 = colr * xv - tr[tx][b] + brv;
            float d2 = cold * xv - td[tx][b] + bdv;
            out[b * N + v] = tanhf(r2) + d2 + xv;
        }
    }
}

extern "C" void kernel_launch(void* const* d_in, const int* in_sizes, int n_in,
                              void* d_out, int out_size, void* d_ws, size_t ws_size,
                              hipStream_t stream) {
    const float* x  = (const float*)d_in[1];
    const int*   ei = (const int*)d_in[2];
    const int*   ej = (const int*)d_in[3];
    const float* wr = (const float*)d_in[4];
    const float* wd = (const float*)d_in[5];
    const float* br = (const float*)d_in[6];
    const float* bd = (const float*)d_in[7];
    float* out = (float*)d_out;

    int E = in_sizes[2];
    int N = in_sizes[6];
    int NB = (N + BKT_NODES - 1) >> BKT_SHIFT;
    (void)out_size; (void)ws_size; (void)n_in;

    // workspace: xth[N*64 f16] | msg[2*N*64 f16] | colsum[2N f32] | gcur[2NB]
    //          | runs[2*NB*RCAP int2]   (~48 MB)
    char* w = (char*)d_ws;
    __half* xth = (__half*)w;    w += (size_t)N * 64 * 2;
    __half* msg = (__half*)w;    w += (size_t)2 * N * 64 * 2;
    float* colsum = (float*)w;   w += (size_t)2 * N * 4;
    int* gcur   = (int*)w;       w += (size_t)2 * NB * 4;
    w = (char*)(((uintptr_t)w + 15) & ~(uintptr_t)15);
    int2* runs  = (int2*)w;

    dim3 tb(64, 16);
    int ntiles = (N + 63) / 64;
    transpose_kernel<<<ntiles, tb, 0, stream>>>(x, xth, gcur, 2 * NB, N);

    int nchunks = (E + CH - 1) / CH;
    partition_kernel<<<nchunks, 512, 0, stream>>>(ei, ej, wr, wd, gcur, runs, E, NB);

    sortgather_kernel<<<4 * NB, 512, 0, stream>>>(gcur, runs, xth, msg, colsum, NB, N);

    final_kernel<<<ntiles, tb, 0, stream>>>(x, msg, colsum, br, bd, out, N);
}